// Round 5
// baseline (347.736 us; speedup 1.0000x reference)
//
#include <hip/hip_runtime.h>

#define NN 10000    // nodes
#define RR 100      // relations
#define EE 5000     // edges per relation
#define D0 2048
#define D1 128
#define D2 64
#define D3 20
#define NE (RR*EE)  // 500000 edges total

using short8  = __attribute__((ext_vector_type(8))) short;
using float4e = __attribute__((ext_vector_type(4))) float;

__device__ __forceinline__ unsigned short f2bf(float f) {
  unsigned int u = __float_as_uint(f);
  unsigned int r = u + 0x7fffu + ((u >> 16) & 1u);   // RNE
  return (unsigned short)(r >> 16);
}
__device__ __forceinline__ float bf2f(unsigned short u) {
  return __uint_as_float(((unsigned int)u) << 16);
}
__device__ __forceinline__ unsigned int pk2(float lo, float hi) {
  return ((unsigned int)f2bf(hi) << 16) | (unsigned int)f2bf(lo);
}

// ---------------------------------------------------------------------------
// CSR build
// ---------------------------------------------------------------------------
__global__ void deg_kernel(const int* __restrict__ ei, int* __restrict__ deg) {
  int gid = blockIdx.x * 256 + threadIdx.x;
  if (gid >= NE) return;
  int r = gid / EE, e = gid - r * EE;
  int d = ei[r * 2 * EE + EE + e];
  atomicAdd(&deg[r * NN + d], 1);
}

__global__ void cnt_kernel(const int* __restrict__ deg, int* __restrict__ cnt) {
  int n = blockIdx.x * 256 + threadIdx.x;
  if (n >= NN) return;
  int s = 0;
  for (int r = 0; r < RR; r++) s += deg[r * NN + n];
  cnt[n] = s;
}

__global__ __launch_bounds__(1024) void scan_kernel(const int* __restrict__ cnt,
                                                    int* __restrict__ off,
                                                    int* __restrict__ cur) {
  __shared__ int wsum[16];
  __shared__ int carry_s;
  const int tid = threadIdx.x;
  const int wv = tid >> 6, lane = tid & 63;
  if (tid == 0) carry_s = 0;
  __syncthreads();
  for (int base = 0; base < NN; base += 1024) {
    int i = base + tid;
    int v = (i < NN) ? cnt[i] : 0;
    int s = v;
#pragma unroll
    for (int d = 1; d < 64; d <<= 1) {
      int t = __shfl_up(s, d, 64);
      if (lane >= d) s += t;
    }
    if (lane == 63) wsum[wv] = s;
    __syncthreads();
    if (wv == 0) {
      int w = (lane < 16) ? wsum[lane] : 0;
#pragma unroll
      for (int d = 1; d < 16; d <<= 1) {
        int t = __shfl_up(w, d, 64);
        if (lane >= d) w += t;
      }
      if (lane < 16) wsum[lane] = w;
    }
    __syncthreads();
    int excl = carry_s + (wv > 0 ? wsum[wv - 1] : 0) + s - v;
    if (i < NN) { off[i] = excl; cur[i] = excl; }
    __syncthreads();
    if (tid == 1023) carry_s += wsum[15];
    __syncthreads();
  }
  if (tid == 0) off[NN] = carry_s;
}

// rec = (r<<14)|src, esc = 1/max(deg,1)
__global__ void scatter_kernel(const int* __restrict__ ei,
                               const int* __restrict__ deg,
                               int* __restrict__ cur, int* __restrict__ rec,
                               float* __restrict__ esc) {
  int gid = blockIdx.x * 256 + threadIdx.x;
  if (gid >= NE) return;
  int r = gid / EE, e = gid - r * EE;
  int s = ei[r * 2 * EE + e];
  int d = ei[r * 2 * EE + EE + e];
  int p = atomicAdd(&cur[d], 1);
  rec[p] = (r << 14) | s;
  esc[p] = 1.0f / fmaxf((float)deg[r * NN + d], 1.0f);
}

// ---------------------------------------------------------------------------
// weight prep (bf16, transposed [n][k] for MFMA B-frag loads)
// ---------------------------------------------------------------------------
__global__ void wtrans_kernel(const float* __restrict__ W,
                              unsigned short* __restrict__ Bt) {
  int idx = blockIdx.x * 256 + threadIdx.x;
  if (idx >= 128 * 2048) return;
  int n = idx >> 11, k = idx & 2047;
  Bt[idx] = f2bf(W[(size_t)k * 128 + n]);
}

__global__ void wc1t_kernel(const float* __restrict__ root1,
                            const float* __restrict__ basis1,
                            unsigned short* __restrict__ Wt) {
  int idx = blockIdx.x * 256 + threadIdx.x;
  if (idx >= 64 * 1152) return;
  int o = idx / 1152, j = idx - o * 1152;
  float v = (j < 128) ? root1[j * 64 + o] : basis1[(j - 128) * 64 + o];
  Wt[idx] = f2bf(v);
}

__global__ void wc2t_kernel(const float* __restrict__ root2,
                            const float* __restrict__ basis2,
                            unsigned short* __restrict__ Wt) {
  int idx = blockIdx.x * 256 + threadIdx.x;
  if (idx >= 32 * 576) return;
  int c = idx / 576, j = idx - c * 576;
  float v = 0.f;
  if (c < 20) v = (j < 64) ? root2[j * 20 + c] : basis2[(j - 64) * 20 + c];
  Wt[idx] = f2bf(v);
}

// ---------------------------------------------------------------------------
// gemm0: xacc += x_drug[:, ks*256:+256] @ drug_w[ks*256:,:]  (K-split 8, atomics)
// bf16 MFMA 16x16x32; tile M=64,N=128; LDS double-buffer, 1 barrier/chunk
// ---------------------------------------------------------------------------
__global__ __launch_bounds__(256) void gemm0_mfma(
    const float* __restrict__ A, const unsigned short* __restrict__ Btw,
    float* __restrict__ xacc) {
  __shared__ unsigned short Asb[2][64][40];
  __shared__ unsigned short Bsb[2][128][40];
  const int tid = threadIdx.x;
  const int m0 = blockIdx.x * 64;
  const int ks = blockIdx.y;          // 0..7, K-slice of 256
  const int wv = tid >> 6, lane = tid & 63;
  const int lrow = lane & 15, quad = lane >> 4;

  const int arow = tid >> 2, aq = tid & 3;
  int gr = m0 + arow; if (gr >= NN) gr = NN - 1;
  const float* Aptr = &A[(size_t)gr * D0 + ks * 256 + aq * 8];
  const unsigned short* Bp0 = &Btw[(size_t)arow * D0 + ks * 256 + aq * 8];
  const unsigned short* Bp1 = &Btw[(size_t)(arow + 64) * D0 + ks * 256 + aq * 8];

  float4 ra[2];
  uint4 rb[2];

#define G0_LOAD(c)                                       \
  { ra[0] = *(const float4*)(Aptr + (c) * 32);           \
    ra[1] = *(const float4*)(Aptr + (c) * 32 + 4);       \
    rb[0] = *(const uint4*)(Bp0 + (c) * 32);             \
    rb[1] = *(const uint4*)(Bp1 + (c) * 32); }

#define G0_STORE(bi)                                                       \
  { uint4 pk;                                                              \
    pk.x = pk2(ra[0].x, ra[0].y); pk.y = pk2(ra[0].z, ra[0].w);            \
    pk.z = pk2(ra[1].x, ra[1].y); pk.w = pk2(ra[1].z, ra[1].w);            \
    *(uint4*)&Asb[bi][arow][aq * 8] = pk;                                  \
    *(uint4*)&Bsb[bi][arow][aq * 8] = rb[0];                               \
    *(uint4*)&Bsb[bi][arow + 64][aq * 8] = rb[1]; }

#define G0_COMPUTE(bi)                                                      \
  { short8 af = *(const short8*)&Asb[bi][wv * 16 + lrow][quad * 8];         \
    _Pragma("unroll")                                                       \
    for (int nt = 0; nt < 8; nt++) {                                        \
      short8 bfr = *(const short8*)&Bsb[bi][nt * 16 + lrow][quad * 8];      \
      acc[nt] = __builtin_amdgcn_mfma_f32_16x16x32_bf16(af, bfr, acc[nt], 0, 0, 0); \
    } }

  float4e acc[8];
#pragma unroll
  for (int i = 0; i < 8; i++) { acc[i][0]=0.f; acc[i][1]=0.f; acc[i][2]=0.f; acc[i][3]=0.f; }

  G0_LOAD(0);
  G0_STORE(0);
  __syncthreads();
#pragma unroll
  for (int c = 0; c < 8; c++) {
    if (c + 1 < 8) G0_LOAD(c + 1);
    G0_COMPUTE(c & 1);
    if (c + 1 < 8) G0_STORE((c + 1) & 1);
    __syncthreads();
  }

#pragma unroll
  for (int nt = 0; nt < 8; nt++) {
    int col = nt * 16 + lrow;
#pragma unroll
    for (int r = 0; r < 4; r++) {
      int row = m0 + wv * 16 + quad * 4 + r;
      if (row < NN)
        atomicAdd(&xacc[(size_t)row * D1 + col], acc[nt][r]);
    }
  }
}

// xb = bf16(xacc)
__global__ void cvt_kernel(const float* __restrict__ xacc,
                           unsigned short* __restrict__ xb) {
  int idx = (blockIdx.x * 256 + threadIdx.x) * 4;
  if (idx >= NN * D1) return;
  float4 a = *(const float4*)&xacc[idx];
  ushort4 o;
  o.x = f2bf(a.x); o.y = f2bf(a.y); o.z = f2bf(a.z); o.w = f2bf(a.w);
  *(ushort4*)&xb[idx] = o;
}

// ---------------------------------------------------------------------------
// agg1e: A1b[n, b*128+i] = bf16( sum_{e->n} esc_e*comp1[r_e,b]*x[src_e,i] )
// one BLOCK per node; 4 waves split the edge range; LDS partial reduce
// ---------------------------------------------------------------------------
__global__ __launch_bounds__(256) void agg1e_kernel(
    const unsigned short* __restrict__ xb, const int* __restrict__ off,
    const int* __restrict__ rec, const float* __restrict__ esc,
    const float* __restrict__ comp, unsigned short* __restrict__ A1b) {
  __shared__ float s_comp[RR * 8];
  __shared__ float part[4][1024];
  const int tid = threadIdx.x;
  for (int i = tid; i < RR * 8; i += 256) s_comp[i] = comp[i];
  const int wv = tid >> 6, lane = tid & 63;
  const int n = blockIdx.x;
  const int beg = off[n], end = off[n + 1];
  const int len = end - beg;
  const int q0 = beg + (len * wv) / 4;
  const int q1 = beg + (len * (wv + 1)) / 4;
  __syncthreads();

  float acc[8][2];
#pragma unroll
  for (int b = 0; b < 8; b++) { acc[b][0] = 0.f; acc[b][1] = 0.f; }

  int idx = q0;
  for (; idx + 1 < q1; idx += 2) {
    int rc0 = rec[idx], rc1 = rec[idx + 1];
    float sc0 = esc[idx], sc1 = esc[idx + 1];
    unsigned int xv0 = *(const unsigned int*)&xb[(size_t)(rc0 & 16383) * D1 + lane * 2];
    unsigned int xv1 = *(const unsigned int*)&xb[(size_t)(rc1 & 16383) * D1 + lane * 2];
    const float* c0 = &s_comp[(rc0 >> 14) * 8];
    const float* c1 = &s_comp[(rc1 >> 14) * 8];
    float x00 = __uint_as_float((xv0 & 0xffffu) << 16);
    float x01 = __uint_as_float(xv0 & 0xffff0000u);
    float x10 = __uint_as_float((xv1 & 0xffffu) << 16);
    float x11 = __uint_as_float(xv1 & 0xffff0000u);
#pragma unroll
    for (int b = 0; b < 8; b++) {
      float w0 = sc0 * c0[b], w1 = sc1 * c1[b];
      acc[b][0] += w0 * x00 + w1 * x10;
      acc[b][1] += w0 * x01 + w1 * x11;
    }
  }
  if (idx < q1) {
    int rc = rec[idx];
    float sc = esc[idx];
    unsigned int xv = *(const unsigned int*)&xb[(size_t)(rc & 16383) * D1 + lane * 2];
    const float* cb = &s_comp[(rc >> 14) * 8];
    float x0 = __uint_as_float((xv & 0xffffu) << 16);
    float x1 = __uint_as_float(xv & 0xffff0000u);
#pragma unroll
    for (int b = 0; b < 8; b++) {
      float w = sc * cb[b];
      acc[b][0] += w * x0;
      acc[b][1] += w * x1;
    }
  }
#pragma unroll
  for (int b = 0; b < 8; b++) {
    part[wv][b * 128 + lane * 2]     = acc[b][0];
    part[wv][b * 128 + lane * 2 + 1] = acc[b][1];
  }
  __syncthreads();
  {
    int o = tid * 4;
    float s0 = part[0][o]     + part[1][o]     + part[2][o]     + part[3][o];
    float s1 = part[0][o + 1] + part[1][o + 1] + part[2][o + 1] + part[3][o + 1];
    float s2 = part[0][o + 2] + part[1][o + 2] + part[2][o + 2] + part[3][o + 2];
    float s3 = part[0][o + 3] + part[1][o + 3] + part[2][o + 3] + part[3][o + 3];
    ushort4 ov; ov.x = f2bf(s0); ov.y = f2bf(s1); ov.z = f2bf(s2); ov.w = f2bf(s3);
    *(ushort4*)&A1b[(size_t)n * 1024 + o] = ov;
  }
}

// ---------------------------------------------------------------------------
// agg2e: A2b[n, b*64+i] = bf16( sum_{e->n} esc_e*comp2[r_e,b]*h[src_e,i] )
// one BLOCK per node; 4 waves split the edge range; LDS partial reduce
// ---------------------------------------------------------------------------
__global__ __launch_bounds__(256) void agg2e_kernel(
    const unsigned short* __restrict__ hb, const int* __restrict__ off,
    const int* __restrict__ rec, const float* __restrict__ esc,
    const float* __restrict__ comp, unsigned short* __restrict__ A2b) {
  __shared__ float s_comp[RR * 8];
  __shared__ float part[4][512];
  const int tid = threadIdx.x;
  for (int i = tid; i < RR * 8; i += 256) s_comp[i] = comp[i];
  const int wv = tid >> 6, lane = tid & 63;
  const int n = blockIdx.x;
  const int beg = off[n], end = off[n + 1];
  const int len = end - beg;
  const int q0 = beg + (len * wv) / 4;
  const int q1 = beg + (len * (wv + 1)) / 4;
  __syncthreads();

  float acc[8];
#pragma unroll
  for (int b = 0; b < 8; b++) acc[b] = 0.f;

  int idx = q0;
  for (; idx + 1 < q1; idx += 2) {
    int rc0 = rec[idx], rc1 = rec[idx + 1];
    float sc0 = esc[idx], sc1 = esc[idx + 1];
    float h0 = bf2f(hb[(size_t)(rc0 & 16383) * D2 + lane]);
    float h1 = bf2f(hb[(size_t)(rc1 & 16383) * D2 + lane]);
    const float* c0 = &s_comp[(rc0 >> 14) * 8];
    const float* c1 = &s_comp[(rc1 >> 14) * 8];
#pragma unroll
    for (int b = 0; b < 8; b++)
      acc[b] += sc0 * c0[b] * h0 + sc1 * c1[b] * h1;
  }
  if (idx < q1) {
    int rc = rec[idx];
    float sc = esc[idx];
    float hv = bf2f(hb[(size_t)(rc & 16383) * D2 + lane]);
    const float* cb = &s_comp[(rc >> 14) * 8];
#pragma unroll
    for (int b = 0; b < 8; b++) acc[b] += sc * cb[b] * hv;
  }
#pragma unroll
  for (int b = 0; b < 8; b++) part[wv][b * 64 + lane] = acc[b];
  __syncthreads();
  {
    int o = tid * 2;
    float s0 = part[0][o]     + part[1][o]     + part[2][o]     + part[3][o];
    float s1 = part[0][o + 1] + part[1][o + 1] + part[2][o + 1] + part[3][o + 1];
    ushort2 ov; ov.x = f2bf(s0); ov.y = f2bf(s1);
    *(ushort2*)&A2b[(size_t)n * 512 + o] = ov;
  }
}

// ---------------------------------------------------------------------------
// hlayer: hb = bf16(relu([xb|A1b](K=1152) @ Wc1T + bias1))
// MFMA, tile M=32 x N=64 (313 blocks), register-prefetch pipeline
// ---------------------------------------------------------------------------
__global__ __launch_bounds__(256) void hlayer_mfma(
    const unsigned short* __restrict__ xb, const unsigned short* __restrict__ A1b,
    const unsigned short* __restrict__ Wt, const float* __restrict__ bias1,
    unsigned short* __restrict__ hb) {
  __shared__ unsigned short Asb[32][40];
  __shared__ unsigned short Bsb[64][40];
  const int tid = threadIdx.x;
  const int m0 = blockIdx.x * 32;
  const int wv = tid >> 6, lane = tid & 63;
  const int lrow = lane & 15, quad = lane >> 4;
  const int mt = wv >> 1, ntb = (wv & 1) * 2;

  const int brow = tid >> 2, bq = tid & 3;
  const int as_row = (tid & 127) >> 2;
  int gr = m0 + as_row; if (gr >= NN) gr = NN - 1;
  const unsigned short* Arow_x = &xb[(size_t)gr * D1 + bq * 8];
  const unsigned short* Arow_a = &A1b[(size_t)gr * 1024 + bq * 8];
  const unsigned short* Bp = &Wt[(size_t)brow * 1152 + bq * 8];

  uint4 ra0, ra1, rb0, rb1;

#define H_LOAD(ra, rb, c)                                                    \
  { int kb = (c) * 32;                                                       \
    if (tid < 128)                                                           \
      ra = (kb < 128) ? *(const uint4*)(Arow_x + kb)                         \
                      : *(const uint4*)(Arow_a + (kb - 128));                \
    rb = *(const uint4*)(Bp + kb); }

#define H_STORE(ra, rb)                                                      \
  { if (tid < 128) *(uint4*)&Asb[as_row][bq * 8] = ra;                       \
    *(uint4*)&Bsb[brow][bq * 8] = rb; }

#define H_COMPUTE()                                                          \
  { short8 af = *(const short8*)&Asb[mt * 16 + lrow][quad * 8];              \
    _Pragma("unroll")                                                        \
    for (int ntl = 0; ntl < 2; ntl++) {                                      \
      short8 bfr = *(const short8*)&Bsb[(ntb + ntl) * 16 + lrow][quad * 8];  \
      acc[ntl] = __builtin_amdgcn_mfma_f32_16x16x32_bf16(af, bfr, acc[ntl], 0, 0, 0); \
    } }

  float4e acc[2];
#pragma unroll
  for (int i = 0; i < 2; i++) { acc[i][0]=0.f; acc[i][1]=0.f; acc[i][2]=0.f; acc[i][3]=0.f; }

  H_LOAD(ra0, rb0, 0);
  for (int c = 0; c < 36; c += 2) {
    H_STORE(ra0, rb0);
    __syncthreads();
    if (c + 1 < 36) H_LOAD(ra1, rb1, c + 1);
    H_COMPUTE();
    __syncthreads();
    H_STORE(ra1, rb1);
    __syncthreads();
    if (c + 2 < 36) H_LOAD(ra0, rb0, c + 2);
    H_COMPUTE();
    __syncthreads();
  }

#pragma unroll
  for (int ntl = 0; ntl < 2; ntl++) {
    int col = (ntb + ntl) * 16 + lrow;
    float bv = bias1[col];
#pragma unroll
    for (int r = 0; r < 4; r++) {
      int row = m0 + mt * 16 + quad * 4 + r;
      if (row < NN)
        hb[(size_t)row * D2 + col] = f2bf(fmaxf(acc[ntl][r] + bv, 0.f));
    }
  }
}

// ---------------------------------------------------------------------------
// out: out = [hb|A2b](K=576) @ Wc2T + bias2
// MFMA, tile M=32 x N=32 (313 blocks), register-prefetch pipeline
// ---------------------------------------------------------------------------
__global__ __launch_bounds__(256) void out_mfma(
    const unsigned short* __restrict__ hb, const unsigned short* __restrict__ A2b,
    const unsigned short* __restrict__ Wt, const float* __restrict__ bias2,
    float* __restrict__ out) {
  __shared__ unsigned short Asb[32][40];
  __shared__ unsigned short Bsb[32][40];
  const int tid = threadIdx.x;
  const int m0 = blockIdx.x * 32;
  const int wv = tid >> 6, lane = tid & 63;
  const int lrow = lane & 15, quad = lane >> 4;
  const int mt = wv >> 1, nt = wv & 1;

  const int srow = (tid & 127) >> 2, sq = tid & 3;
  int gr = m0 + srow; if (gr >= NN) gr = NN - 1;
  const unsigned short* Arow_h = &hb[(size_t)gr * D2 + sq * 8];
  const unsigned short* Arow_a = &A2b[(size_t)gr * 512 + sq * 8];
  const unsigned short* Bp = &Wt[(size_t)srow * 576 + sq * 8];

  uint4 r0, r1;

#define O_LOAD(rg, c)                                                        \
  { int kb = (c) * 32;                                                       \
    if (tid < 128)                                                           \
      rg = (kb < 64) ? *(const uint4*)(Arow_h + kb)                          \
                     : *(const uint4*)(Arow_a + (kb - 64));                  \
    else                                                                     \
      rg = *(const uint4*)(Bp + kb); }

#define O_STORE(rg)                                                          \
  { if (tid < 128) *(uint4*)&Asb[srow][sq * 8] = rg;                         \
    else           *(uint4*)&Bsb[srow][sq * 8] = rg; }

#define O_COMPUTE()                                                          \
  { short8 af = *(const short8*)&Asb[mt * 16 + lrow][quad * 8];              \
    short8 bfr = *(const short8*)&Bsb[nt * 16 + lrow][quad * 8];             \
    acc = __builtin_amdgcn_mfma_f32_16x16x32_bf16(af, bfr, acc, 0, 0, 0); }

  float4e acc;
  acc[0]=0.f; acc[1]=0.f; acc[2]=0.f; acc[3]=0.f;

  O_LOAD(r0, 0);
  for (int c = 0; c < 18; c += 2) {
    O_STORE(r0);
    __syncthreads();
    if (c + 1 < 18) O_LOAD(r1, c + 1);
    O_COMPUTE();
    __syncthreads();
    O_STORE(r1);
    __syncthreads();
    if (c + 2 < 18) O_LOAD(r0, c + 2);
    O_COMPUTE();
    __syncthreads();
  }

  int col = nt * 16 + lrow;
  if (col < D3) {
    float bv = bias2[col];
#pragma unroll
    for (int r = 0; r < 4; r++) {
      int row = m0 + mt * 16 + quad * 4 + r;
      if (row < NN)
        out[(size_t)row * D3 + col] = acc[r] + bv;
    }
  }
}

// ---------------------------------------------------------------------------
extern "C" void kernel_launch(void* const* d_in, const int* in_sizes, int n_in,
                              void* d_out, int out_size, void* d_ws,
                              size_t ws_size, hipStream_t stream) {
  const float* x_drug = (const float*)d_in[0];
  const float* drug_w = (const float*)d_in[1];
  const int*   ei     = (const int*)d_in[2];
  const float* basis1 = (const float*)d_in[3];
  const float* comp1  = (const float*)d_in[4];
  const float* root1  = (const float*)d_in[5];
  const float* bias1  = (const float*)d_in[6];
  const float* basis2 = (const float*)d_in[7];
  const float* comp2  = (const float*)d_in[8];
  const float* root2  = (const float*)d_in[9];
  const float* bias2  = (const float*)d_in[10];
  float* out = (float*)d_out;

  float* ws = (float*)d_ws;
  int*   deg  = (int*)ws;                          // 1,000,000
  int*   cnt  = deg + 1000000;                     // 10,016
  int*   off  = cnt + 10016;                       // 10,016
  int*   cur  = off + 10016;                       // 10,016
  int*   rec  = cur + 10016;                       // 500,000
  float* esc  = (float*)(rec + 500000);            // 500,000
  unsigned short* xb   = (unsigned short*)(esc + 500000);          // 640,000 f
  unsigned short* hb   = (unsigned short*)((float*)xb + 640000);   // 320,000 f
  unsigned short* Btw  = (unsigned short*)((float*)hb + 320000);   // 131,072 f
  unsigned short* Wc1T = (unsigned short*)((float*)Btw + 131072);  // 36,864 f
  unsigned short* Wc2T = (unsigned short*)((float*)Wc1T + 36864);  // 9,216 f
  float* R1 = (float*)Wc2T + 9216;                 // 5,120,000 floats shared
  float* xacc = R1;                                // 1,280,000 fp32 accumulator
  unsigned short* A1b = (unsigned short*)R1;       // aliases xacc (after cvt)
  unsigned short* A2b = (unsigned short*)R1;       // aliases A1b (after hlayer)

  hipMemsetAsync(deg, 0, (size_t)1000000 * 4, stream);
  hipMemsetAsync(xacc, 0, (size_t)1280000 * 4, stream);

  // CSR build
  deg_kernel<<<(NE + 255) / 256, 256, 0, stream>>>(ei, deg);
  cnt_kernel<<<(NN + 255) / 256, 256, 0, stream>>>(deg, cnt);
  scan_kernel<<<1, 1024, 0, stream>>>(cnt, off, cur);
  scatter_kernel<<<(NE + 255) / 256, 256, 0, stream>>>(ei, deg, cur, rec, esc);

  // weights
  wtrans_kernel<<<(128 * 2048 + 255) / 256, 256, 0, stream>>>(drug_w, Btw);
  wc1t_kernel<<<(64 * 1152 + 255) / 256, 256, 0, stream>>>(root1, basis1, Wc1T);
  wc2t_kernel<<<(32 * 576 + 255) / 256, 256, 0, stream>>>(root2, basis2, Wc2T);

  // x = x_drug @ drug_w (bf16 MFMA, K-split 8 + fp32 atomic accumulate)
  gemm0_mfma<<<dim3(157, 8), 256, 0, stream>>>(x_drug, Btw, xacc);
  cvt_kernel<<<(NN * D1 / 4 + 255) / 256, 256, 0, stream>>>(xacc, xb);

  // layer 1
  agg1e_kernel<<<NN, 256, 0, stream>>>(xb, off, rec, esc, comp1, A1b);
  hlayer_mfma<<<(NN + 31) / 32, 256, 0, stream>>>(xb, A1b, Wc1T, bias1, hb);

  // layer 2
  agg2e_kernel<<<NN, 256, 0, stream>>>(hb, off, rec, esc, comp2, A2b);
  out_mfma<<<(NN + 31) / 32, 256, 0, stream>>>(hb, A2b, Wc2T, bias2, out);
}